// Round 17
// baseline (3695.878 us; speedup 1.0000x reference)
//
#include <hip/hip_runtime.h>
#include <cstdint>
#include <cstddef>

// Problem constants (AugmentedLstm: B=64, T=512, D=512, H=512)
#define BB 64
#define TT 512
#define DD 512
#define HH 512
#define SIXH 3072
#define NWG 32           // persistent recurrence workgroups (j-slices of 16)

typedef __attribute__((ext_vector_type(8))) short bf16x8;
typedef __attribute__((ext_vector_type(4))) float f32x4;
typedef __attribute__((ext_vector_type(4))) unsigned short u16x4;
typedef __attribute__((ext_vector_type(4))) int i32x4;

// ---- ws layout (byte offsets) ---------------------------------------------
// v10: h ping-pong is TAGGED: per (slot,b,quad) one 16B record
//      [tag32 | 4 x bf16 h | tag32]; 2 x 64 x 128 x 16B = 256 KB.
#define WS_FLAGS 0u          // 2 ints: [0] fp32-inputs flag, [1] int64-lengths flag
#define WS_H2    256u        // tagged h ping-pong (262144 B)
#define WS_C     262400u     // [BB][HH] float c (131072 B)
#define WS_XB    393472u     // x as bf16 [BB][TT][DD] (33554432 B)
#define WS_WB    33947904u   // w_in as bf16 [6H][DD] (3145728 B)
#define WS_BF    37093632u   // b_in as f32 [6H] (12288 B)
#define WS_PROJ  37105920u   // proj chunk: [b][tl][6H] bf16, Tc*BB rows

// Coherent (L2-bypassing, L3-visible) accesses via explicit sc0 sc1.
#define CLOAD16(dst, ptr) \
    asm volatile("global_load_dwordx4 %0, %1, off sc0 sc1" : "=v"(dst) : "v"(ptr))
#define CLOAD16O(dst, ptr, OFF) \
    asm volatile("global_load_dwordx4 %0, %1, off offset:%c2 sc0 sc1" \
                 : "=v"(dst) : "v"(ptr), "i"(OFF))
#define CSTORE16(ptr, val) \
    asm volatile("global_store_dwordx4 %0, %1, off sc0 sc1" :: "v"(ptr), "v"(val))

__device__ __forceinline__ float bf2f(unsigned short u) {
    union { unsigned int i; float f; } v; v.i = ((unsigned int)u) << 16; return v.f;
}
__device__ __forceinline__ unsigned short f2bf(float f) {
    union { unsigned int i; float f; } v; v.f = f;
    unsigned int r = v.i + 0x7FFFu + ((v.i >> 16) & 1u);  // RNE
    return (unsigned short)(r >> 16);
}
__device__ __forceinline__ float sigm(float x) { return 1.0f / (1.0f + __expf(-x)); }
__device__ __forceinline__ float tanh_fast(float x) {
    return 1.0f - 2.0f / (__expf(2.0f * x) + 1.0f);   // NaN-free, exact at +-inf
}

// vectorized f32->bf16x8: two float4 loads (32B-aligned at all call sites)
__device__ __forceinline__ bf16x8 cvt8v(const float* p) {
    const float4 a = *(const float4*)p;
    const float4 b = *(const float4*)(p + 4);
    bf16x8 o;
    o[0] = (short)f2bf(a.x); o[1] = (short)f2bf(a.y);
    o[2] = (short)f2bf(a.z); o[3] = (short)f2bf(a.w);
    o[4] = (short)f2bf(b.x); o[5] = (short)f2bf(b.y);
    o[6] = (short)f2bf(b.z); o[7] = (short)f2bf(b.w);
    return o;
}

// ---------------------------------------------------------------------------
// Detect input dtypes from raw bits (logic proven rounds 2-5).
// ---------------------------------------------------------------------------
__global__ void detect_kernel(const unsigned short* __restrict__ x16,
                              const int* __restrict__ len32,
                              int* __restrict__ flags) {
    const int lane = threadIdx.x;   // 64
    int bad = 0;
    for (int i = lane; i < 256; i += 64)
        if (fabsf(bf2f(x16[i])) > 1e4f) bad++;
#pragma unroll
    for (int off = 32; off; off >>= 1) bad += __shfl_down(bad, off);
    if (lane == 0) {
        flags[0] = (bad >= 16) ? 1 : 0;
        flags[1] = (len32[1] == 0 && len32[3] == 0 && len32[5] == 0) ? 1 : 0;
    }
}

// ---------------------------------------------------------------------------
// One-shot input conversion (proven r9): x,w_in -> bf16; b_in -> f32 in ws.
// ---------------------------------------------------------------------------
__global__ __launch_bounds__(256) void convert_kernel(
    const void* __restrict__ xv, const void* __restrict__ wv,
    const void* __restrict__ bv,
    unsigned short* __restrict__ xb, unsigned short* __restrict__ wb,
    float* __restrict__ bf, const int* __restrict__ flags)
{
    const int fp32 = flags[0];
    const size_t NX = (size_t)BB * TT * DD;   // 16,777,216
    const size_t NW = (size_t)SIXH * DD;      //  1,572,864
    const size_t tid = (size_t)blockIdx.x * blockDim.x + threadIdx.x;
    const size_t stride = (size_t)gridDim.x * blockDim.x;

    if (fp32) {
        const float* xf = (const float*)xv;
        for (size_t i = tid * 4; i < NX; i += stride * 4) {
            const float4 v = *(const float4*)(xf + i);
            u16x4 o; o[0] = f2bf(v.x); o[1] = f2bf(v.y); o[2] = f2bf(v.z); o[3] = f2bf(v.w);
            *(u16x4*)(xb + i) = o;
        }
        const float* wf = (const float*)wv;
        for (size_t i = tid * 4; i < NW; i += stride * 4) {
            const float4 v = *(const float4*)(wf + i);
            u16x4 o; o[0] = f2bf(v.x); o[1] = f2bf(v.y); o[2] = f2bf(v.z); o[3] = f2bf(v.w);
            *(u16x4*)(wb + i) = o;
        }
        const float* bvf = (const float*)bv;
        for (size_t i = tid; i < SIXH; i += stride) bf[i] = bvf[i];
    } else {
        const unsigned short* xs = (const unsigned short*)xv;
        for (size_t i = tid * 4; i < NX; i += stride * 4)
            *(u16x4*)(xb + i) = *(const u16x4*)(xs + i);
        const unsigned short* wsrc = (const unsigned short*)wv;
        for (size_t i = tid * 4; i < NW; i += stride * 4)
            *(u16x4*)(wb + i) = *(const u16x4*)(wsrc + i);
        const unsigned short* bs = (const unsigned short*)bv;
        for (size_t i = tid; i < SIXH; i += stride) bf[i] = bf2f(bs[i]);
    }
}

// ---------------------------------------------------------------------------
// Proj chunk GEMM v2 (proven r10): 64m x 192n per block, A reused across 3
// n-tiles.
// ---------------------------------------------------------------------------
__global__ __launch_bounds__(256) void proj_kernel(
    const unsigned short* __restrict__ xb, const unsigned short* __restrict__ wb,
    const float* __restrict__ bf, unsigned short* __restrict__ projc,
    const int* __restrict__ flags, const int* __restrict__ len32,
    int t0, int tc_shift)
{
    const int Tc  = 1 << tc_shift;
    {
        const int mb  = blockIdx.y * 64;
        const int bq  = mb >> tc_shift;
        const int tl0 = mb & (Tc - 1);
        const int len_b = flags[1] ? len32[2 * bq] : len32[bq];
        if (t0 + tl0 >= len_b) return;
    }

    const int tid  = threadIdx.x;
    const int wave = tid >> 6;
    const int lane = tid & 63;
    const int q    = lane >> 4;
    const int r    = lane & 15;

    const int m_blk  = blockIdx.y * 64 + (wave >> 1) * 32;
    const int n_base = blockIdx.x * 192 + (wave & 1) * 32;
    const int b      = m_blk >> tc_shift;
    const int tl     = m_blk & (Tc - 1);

    const size_t xrow0 = (size_t)(b * TT + t0 + tl + r) * DD;
    const size_t xrow1 = (size_t)(b * TT + t0 + tl + 16 + r) * DD;

    f32x4 acc[3][2][2] = {};
    const int koff = q * 8;
    for (int k0 = 0; k0 < DD; k0 += 32) {
        const int k = k0 + koff;
        const bf16x8 a0 = *(const bf16x8*)(xb + xrow0 + k);
        const bf16x8 a1 = *(const bf16x8*)(xb + xrow1 + k);
#pragma unroll
        for (int nt = 0; nt < 3; nt++) {
            const size_t wrow0 = (size_t)(n_base + nt * 64 + r) * DD;
            const size_t wrow1 = (size_t)(n_base + nt * 64 + 16 + r) * DD;
            bf16x8 b0 = *(const bf16x8*)(wb + wrow0 + k);
            bf16x8 b1 = *(const bf16x8*)(wb + wrow1 + k);
            acc[nt][0][0] = __builtin_amdgcn_mfma_f32_16x16x32_bf16(a0, b0, acc[nt][0][0], 0, 0, 0);
            acc[nt][0][1] = __builtin_amdgcn_mfma_f32_16x16x32_bf16(a0, b1, acc[nt][0][1], 0, 0, 0);
            acc[nt][1][0] = __builtin_amdgcn_mfma_f32_16x16x32_bf16(a1, b0, acc[nt][1][0], 0, 0, 0);
            acc[nt][1][1] = __builtin_amdgcn_mfma_f32_16x16x32_bf16(a1, b1, acc[nt][1][1], 0, 0, 0);
        }
    }

#pragma unroll
    for (int nt = 0; nt < 3; nt++)
#pragma unroll
        for (int mi = 0; mi < 2; mi++)
#pragma unroll
            for (int ni = 0; ni < 2; ni++) {
                const int n = n_base + nt * 64 + ni * 16 + r;
                const float bias = bf[n];
#pragma unroll
                for (int rr = 0; rr < 4; rr++) {
                    const int m = m_blk + mi * 16 + q * 4 + rr;
                    projc[(size_t)m * SIXH + n] = f2bf(acc[nt][mi][ni][rr] + bias);
                }
            }
}

// ---------------------------------------------------------------------------
// Persistent recurrence kernel v10b. Grid: NWG=32 x 256 threads (4 waves).
// Wave w owns batches [w*16, w*16+16); block owns j in [wg*16, wg*16+16).
//
// TAG-IN-DATA handshake (see r10 analysis): producer stores each 4-j h-quad
// as one aligned 16B record [tag | h(8B) | tag], tag = t+1, fire-and-forget
// (no vmcnt drain, no flag). Consumer polls by re-loading its 32 records
// until all tags == t; on match the h data is ALREADY in registers
// (detect+load = one round trip). Depth-2 safety: tag t+2 is only stored
// after its producer saw all tags t+1, which are only published after every
// wave consumed its step-t loads.
//
// v10b adds a POLL WATCHDOG (65536 iters ~ 13ms >> normal ~10 iters): if a
// record never becomes visible (hypothesized cause of r15's container
// death), the wave breaks out with stale data -> bench completes with
// passed:false instead of hanging the GPU. Healthy path unchanged.
// ---------------------------------------------------------------------------
__global__ __launch_bounds__(256, 1) void rec_kernel(
    const unsigned short* __restrict__ projc,
    const void* __restrict__ wsv, const void* __restrict__ bsv,
    const int* __restrict__ len32,
    unsigned int* __restrict__ hbuf2, float* __restrict__ cbuf,
    void* __restrict__ outv,
    const int* __restrict__ flags, int t0, int Tc)
{
    const int fp32 = flags[0], i64 = flags[1];
    const int tid  = threadIdx.x;
    const int wv   = tid >> 6;    // wave = batch group (0..3)
    const int lane = tid & 63;
    const int q    = lane >> 4;
    const int r    = lane & 15;
    const int j0   = blockIdx.x * 16;
    const int b    = wv * 16 + r;              // this lane's batch

    // frag-linear W_state slice: [5 gates][16 ki][64 lanes][8 ushort] = 80 KB
    __shared__ unsigned short wlds[5 * 16 * 64 * 8];

    for (int v = tid; v < 5 * 16 * 64; v += 256) {
        const int g  = v >> 10;
        const int ki = (v >> 6) & 15;
        const int ln = v & 63;
        const size_t gaddr = (size_t)(g * HH + j0 + (ln & 15)) * HH + ki * 32 + (ln >> 4) * 8;
        bf16x8 w8;
        if (fp32) w8 = cvt8v((const float*)wsv + gaddr);
        else      w8 = *(const bf16x8*)((const unsigned short*)wsv + gaddr);
        *(bf16x8*)&wlds[(size_t)v * 8] = w8;
    }

    // per-lane persistent state: lane owns batch b x (j = j0+q*4+jj)
    float bs[5][4];
#pragma unroll
    for (int g = 0; g < 5; g++)
#pragma unroll
        for (int jj = 0; jj < 4; jj++)
            bs[g][jj] = fp32 ? ((const float*)bsv)[g * HH + j0 + q * 4 + jj]
                             : bf2f(((const unsigned short*)bsv)[g * HH + j0 + q * 4 + jj]);

    const int len = i64 ? len32[2 * b] : len32[b];

    // PER-GROUP Lmax: max over this wave's 16 batches (uniform within wave)
    int lmax_g = 0;
    for (int i = wv * 16; i < wv * 16 + 16; i++) {
        const int li = i64 ? len32[2 * i] : len32[i];
        lmax_g = (li > lmax_g) ? li : lmax_g;
    }

    float creg[4];
#pragma unroll
    for (int jj = 0; jj < 4; jj++)
        creg[jj] = cbuf[b * HH + j0 + q * 4 + jj];

    // initial projc gate inputs for tl = 0 (overlaps the wlds staging above)
    u16x4 pv[6];
    {
        const unsigned short* pb = projc + (size_t)b * Tc * SIXH + j0 + q * 4;
#pragma unroll
        for (int g = 0; g < 6; g++) pv[g] = *(const u16x4*)(pb + g * HH);
    }

    __syncthreads();   // wlds ready (only barrier in the kernel)

    union HU { i32x4 i; bf16x8 b; };
    union P8 { unsigned short s[4]; unsigned long long u; };

    // this lane's quad record for PRODUCING: quad index j0/4 + q
    // this lane's row base for CONSUMING: batch b, quads (ki*8 + q*2 + s)
    // record = 4 dwords; row = 128 records = 512 dwords.

    for (int t = t0; t < t0 + Tc; t++) {
        // ---- dead tail: this GROUP is done past lmax_g; no sync, no GEMM ----
        if (t >= lmax_g) {
            if (fp32) {
                float* op = (float*)outv + ((size_t)b * TT + t) * HH + j0 + q * 4;
                *(float4*)op = make_float4(0.f, 0.f, 0.f, 0.f);
            } else {
                unsigned short* op = (unsigned short*)outv + ((size_t)b * TT + t) * HH + j0 + q * 4;
                *(unsigned long long*)op = 0ull;
            }
            continue;
        }

        // ---- gather h(t): 32 tagged 16B records; poll until tags == t ----
        // base covers quads q*2 + ki*8 + s via immediate offset ki*128 + s*16
        const unsigned int* hrow =
            hbuf2 + ((size_t)((t & 1) * BB + b) * 128 + q * 2) * 4;
        i32x4 hq[32];
#define ISSUE_H_LOADS()                                                     \
        _Pragma("unroll")                                                   \
        for (int ki = 0; ki < 16; ki++) {                                   \
            CLOAD16O(hq[2 * ki],     hrow, ki * 128);                       \
            CLOAD16O(hq[2 * ki + 1], hrow, ki * 128 + 16);                  \
        }
        if (t > t0) {
            int spin = 0;
            for (;;) {
                ISSUE_H_LOADS();
                asm volatile("s_waitcnt vmcnt(0)" ::: "memory");
                __builtin_amdgcn_sched_barrier(0);
                unsigned bad = 0;
#pragma unroll
                for (int i = 0; i < 32; i++)
                    bad |= (unsigned)((hq[i][0] ^ t) | (hq[i][3] ^ t));
                if (__all(bad == 0)) break;
                if (++spin > 65536) break;   // watchdog: hang -> wrong result, not GPU death
            }
        } else {
            // chunk start: producers finished in the previous kernel launch
            ISSUE_H_LOADS();
            asm volatile("s_waitcnt vmcnt(0)" ::: "memory");
            __builtin_amdgcn_sched_barrier(0);
        }
#undef ISSUE_H_LOADS

        // --- GEMM: data already in registers; extract 8 bf16 per ki ---
        f32x4 acc[5] = {};
#pragma unroll
        for (int ki = 0; ki < 16; ki++) {
            HU u;
            u.i = (i32x4){ hq[2 * ki][1], hq[2 * ki][2],
                           hq[2 * ki + 1][1], hq[2 * ki + 1][2] };
#pragma unroll
            for (int g = 0; g < 5; g++) {
                bf16x8 aw = *(const bf16x8*)&wlds[((g * 16 + ki) * 64 + lane) * 8];
                acc[g] = __builtin_amdgcn_mfma_f32_16x16x32_bf16(aw, u.b, acc[g], 0, 0, 0);
            }
        }

        // --- epilogue: lane owns batch b x 4 consecutive j ---
        P8 hp;
        float ov4[4];
#pragma unroll
        for (int jj = 0; jj < 4; jj++) {
            const float i_g = sigm(bf2f(pv[0][jj]) + acc[0][jj] + bs[0][jj]);
            const float f_g = sigm(bf2f(pv[1][jj]) + acc[1][jj] + bs[1][jj]);
            const float g_t = tanh_fast(bf2f(pv[2][jj]) + acc[2][jj] + bs[2][jj]);
            const float o_g = sigm(bf2f(pv[3][jj]) + acc[3][jj] + bs[3][jj]);
            const float hw  = sigm(bf2f(pv[4][jj]) + acc[4][jj] + bs[4][jj]);

            float c_new = i_g * g_t + f_g * creg[jj];
            float ov = o_g * tanh_fast(c_new);
            ov = hw * ov + (1.0f - hw) * bf2f(pv[5][jj]);
            if (t >= len) { ov = 0.0f; c_new = 0.0f; }
            creg[jj] = c_new;
            ov4[jj] = ov;
            hp.s[jj] = f2bf(ov);
        }

        // --- publish h(t+1): ONE tagged 16B store, fire-and-forget ---
        {
            i32x4 st;
            st[0] = t + 1;
            st[1] = (int)(unsigned int)(hp.u & 0xffffffffull);
            st[2] = (int)(unsigned int)(hp.u >> 32);
            st[3] = t + 1;
            unsigned int* hw_ = hbuf2 +
                ((size_t)(((t + 1) & 1) * BB + b) * 128 + (j0 >> 2) + q) * 4;
            CSTORE16(hw_, st);
        }

        // --- off-critical-path: output store + projc prefetch for t+1 ---
        if (fp32) {
            float* op = (float*)outv + ((size_t)b * TT + t) * HH + j0 + q * 4;
            *(float4*)op = make_float4(ov4[0], ov4[1], ov4[2], ov4[3]);
        } else {
            unsigned short* op = (unsigned short*)outv + ((size_t)b * TT + t) * HH + j0 + q * 4;
            *(unsigned long long*)op = hp.u;
        }
        const int tln = t - t0 + 1;
        if (tln < Tc) {
            const unsigned short* pb = projc + ((size_t)b * Tc + tln) * SIXH + j0 + q * 4;
#pragma unroll
            for (int g = 0; g < 6; g++) pv[g] = *(const u16x4*)(pb + g * HH);
        }
    }

    // persist c for chunked mode
#pragma unroll
    for (int jj = 0; jj < 4; jj++)
        cbuf[b * HH + j0 + q * 4 + jj] = creg[jj];
}

// ---------------------------------------------------------------------------
extern "C" void kernel_launch(void* const* d_in, const int* in_sizes, int n_in,
                              void* d_out, int out_size, void* d_ws, size_t ws_size,
                              hipStream_t stream) {
    const void* xv      = d_in[0];
    const int*  len     = (const int*)d_in[1];
    const void* w_in    = d_in[2];
    const void* b_in    = d_in[3];
    const void* w_state = d_in[4];
    const void* b_state = d_in[5];

    char* ws = (char*)d_ws;
    int* flags  = (int*)(ws + WS_FLAGS);
    unsigned int* hbuf2 = (unsigned int*)(ws + WS_H2);
    float* cbuf = (float*)(ws + WS_C);
    unsigned short* xb = (unsigned short*)(ws + WS_XB);
    unsigned short* wb = (unsigned short*)(ws + WS_WB);
    float* bf = (float*)(ws + WS_BF);
    unsigned short* projc = (unsigned short*)(ws + WS_PROJ);

    // Largest proj chunk (timesteps, power of 2, >= 64) fitting ws.
    int tc_shift = 9;
    while (tc_shift > 6 &&
           WS_PROJ + ((size_t)BB << tc_shift) * SIXH * 2 > ws_size) tc_shift--;
    const int Tc = 1 << tc_shift;

    detect_kernel<<<1, 64, 0, stream>>>((const unsigned short*)xv, len, flags);
    // zero tagged h (tags=0 == first step) + c
    hipMemsetAsync(ws + WS_H2, 0, WS_XB - WS_H2, stream);
    convert_kernel<<<2048, 256, 0, stream>>>(xv, w_in, b_in, xb, wb, bf, flags);

    for (int c = 0; c < TT / Tc; c++) {
        const int t0 = c * Tc;
        proj_kernel<<<dim3(SIXH / 192, (BB << tc_shift) >> 6), 256, 0, stream>>>(
            xb, wb, bf, projc, flags, len, t0, tc_shift);
        rec_kernel<<<NWG, 256, 0, stream>>>(projc, w_state, b_state, len,
                                            hbuf2, cbuf, d_out, flags, t0, Tc);
    }
}

// Round 18
// 2965.770 us; speedup vs baseline: 1.2462x; 1.2462x over previous
//
#include <hip/hip_runtime.h>
#include <cstdint>
#include <cstddef>

// Problem constants (AugmentedLstm: B=64, T=512, D=512, H=512)
#define BB 64
#define TT 512
#define DD 512
#define HH 512
#define SIXH 3072
#define NWG 32           // persistent recurrence workgroups (j-slices of 16)

typedef __attribute__((ext_vector_type(8))) short bf16x8;
typedef __attribute__((ext_vector_type(4))) float f32x4;
typedef __attribute__((ext_vector_type(4))) unsigned short u16x4;
typedef __attribute__((ext_vector_type(4))) int i32x4;

// ---- ws layout (byte offsets) ---------------------------------------------
// Tagged h ping-pong: per (slot,b,quad) one 16B record
//      [tag32 | 4 x bf16 h | tag32]; 2 x 64 x 128 x 16B = 256 KB.
#define WS_FLAGS 0u          // 2 ints: [0] fp32-inputs flag, [1] int64-lengths flag
#define WS_H2    256u        // tagged h ping-pong (262144 B)
#define WS_C     262400u     // [BB][HH] float c (131072 B)
#define WS_XB    393472u     // x as bf16 [BB][TT][DD] (33554432 B)
#define WS_WB    33947904u   // w_in as bf16 [6H][DD] (3145728 B)
#define WS_BF    37093632u   // b_in as f32 [6H] (12288 B)
#define WS_PROJ  37105920u   // proj chunk: [b][tl][6H] bf16, Tc*BB rows

// Coherent (L2-bypassing, L3-visible) accesses via explicit sc0 sc1.
#define CLOAD16O(dst, ptr, OFF) \
    asm volatile("global_load_dwordx4 %0, %1, off offset:%c2 sc0 sc1" \
                 : "=v"(dst) : "v"(ptr), "i"(OFF))
#define CLOAD4(dst, ptr) \
    asm volatile("global_load_dword %0, %1, off sc0 sc1" : "=v"(dst) : "v"(ptr))
#define CSTORE16(ptr, val) \
    asm volatile("global_store_dwordx4 %0, %1, off sc0 sc1" :: "v"(ptr), "v"(val))

__device__ __forceinline__ float bf2f(unsigned short u) {
    union { unsigned int i; float f; } v; v.i = ((unsigned int)u) << 16; return v.f;
}
__device__ __forceinline__ unsigned short f2bf(float f) {
    union { unsigned int i; float f; } v; v.f = f;
    unsigned int r = v.i + 0x7FFFu + ((v.i >> 16) & 1u);  // RNE
    return (unsigned short)(r >> 16);
}
__device__ __forceinline__ float sigm(float x) { return 1.0f / (1.0f + __expf(-x)); }
__device__ __forceinline__ float tanh_fast(float x) {
    return 1.0f - 2.0f / (__expf(2.0f * x) + 1.0f);   // NaN-free, exact at +-inf
}

// vectorized f32->bf16x8: two float4 loads (32B-aligned at all call sites)
__device__ __forceinline__ bf16x8 cvt8v(const float* p) {
    const float4 a = *(const float4*)p;
    const float4 b = *(const float4*)(p + 4);
    bf16x8 o;
    o[0] = (short)f2bf(a.x); o[1] = (short)f2bf(a.y);
    o[2] = (short)f2bf(a.z); o[3] = (short)f2bf(a.w);
    o[4] = (short)f2bf(b.x); o[5] = (short)f2bf(b.y);
    o[6] = (short)f2bf(b.z); o[7] = (short)f2bf(b.w);
    return o;
}

// ---------------------------------------------------------------------------
// Detect input dtypes from raw bits (logic proven rounds 2-5).
// ---------------------------------------------------------------------------
__global__ void detect_kernel(const unsigned short* __restrict__ x16,
                              const int* __restrict__ len32,
                              int* __restrict__ flags) {
    const int lane = threadIdx.x;   // 64
    int bad = 0;
    for (int i = lane; i < 256; i += 64)
        if (fabsf(bf2f(x16[i])) > 1e4f) bad++;
#pragma unroll
    for (int off = 32; off; off >>= 1) bad += __shfl_down(bad, off);
    if (lane == 0) {
        flags[0] = (bad >= 16) ? 1 : 0;
        flags[1] = (len32[1] == 0 && len32[3] == 0 && len32[5] == 0) ? 1 : 0;
    }
}

// ---------------------------------------------------------------------------
// One-shot input conversion (proven r9): x,w_in -> bf16; b_in -> f32 in ws.
// ---------------------------------------------------------------------------
__global__ __launch_bounds__(256) void convert_kernel(
    const void* __restrict__ xv, const void* __restrict__ wv,
    const void* __restrict__ bv,
    unsigned short* __restrict__ xb, unsigned short* __restrict__ wb,
    float* __restrict__ bf, const int* __restrict__ flags)
{
    const int fp32 = flags[0];
    const size_t NX = (size_t)BB * TT * DD;   // 16,777,216
    const size_t NW = (size_t)SIXH * DD;      //  1,572,864
    const size_t tid = (size_t)blockIdx.x * blockDim.x + threadIdx.x;
    const size_t stride = (size_t)gridDim.x * blockDim.x;

    if (fp32) {
        const float* xf = (const float*)xv;
        for (size_t i = tid * 4; i < NX; i += stride * 4) {
            const float4 v = *(const float4*)(xf + i);
            u16x4 o; o[0] = f2bf(v.x); o[1] = f2bf(v.y); o[2] = f2bf(v.z); o[3] = f2bf(v.w);
            *(u16x4*)(xb + i) = o;
        }
        const float* wf = (const float*)wv;
        for (size_t i = tid * 4; i < NW; i += stride * 4) {
            const float4 v = *(const float4*)(wf + i);
            u16x4 o; o[0] = f2bf(v.x); o[1] = f2bf(v.y); o[2] = f2bf(v.z); o[3] = f2bf(v.w);
            *(u16x4*)(wb + i) = o;
        }
        const float* bvf = (const float*)bv;
        for (size_t i = tid; i < SIXH; i += stride) bf[i] = bvf[i];
    } else {
        const unsigned short* xs = (const unsigned short*)xv;
        for (size_t i = tid * 4; i < NX; i += stride * 4)
            *(u16x4*)(xb + i) = *(const u16x4*)(xs + i);
        const unsigned short* wsrc = (const unsigned short*)wv;
        for (size_t i = tid * 4; i < NW; i += stride * 4)
            *(u16x4*)(wb + i) = *(const u16x4*)(wsrc + i);
        const unsigned short* bs = (const unsigned short*)bv;
        for (size_t i = tid; i < SIXH; i += stride) bf[i] = bf2f(bs[i]);
    }
}

// ---------------------------------------------------------------------------
// Proj chunk GEMM v2 (proven r10): 64m x 192n per block, A reused across 3
// n-tiles.
// ---------------------------------------------------------------------------
__global__ __launch_bounds__(256) void proj_kernel(
    const unsigned short* __restrict__ xb, const unsigned short* __restrict__ wb,
    const float* __restrict__ bf, unsigned short* __restrict__ projc,
    const int* __restrict__ flags, const int* __restrict__ len32,
    int t0, int tc_shift)
{
    const int Tc  = 1 << tc_shift;
    {
        const int mb  = blockIdx.y * 64;
        const int bq  = mb >> tc_shift;
        const int tl0 = mb & (Tc - 1);
        const int len_b = flags[1] ? len32[2 * bq] : len32[bq];
        if (t0 + tl0 >= len_b) return;
    }

    const int tid  = threadIdx.x;
    const int wave = tid >> 6;
    const int lane = tid & 63;
    const int q    = lane >> 4;
    const int r    = lane & 15;

    const int m_blk  = blockIdx.y * 64 + (wave >> 1) * 32;
    const int n_base = blockIdx.x * 192 + (wave & 1) * 32;
    const int b      = m_blk >> tc_shift;
    const int tl     = m_blk & (Tc - 1);

    const size_t xrow0 = (size_t)(b * TT + t0 + tl + r) * DD;
    const size_t xrow1 = (size_t)(b * TT + t0 + tl + 16 + r) * DD;

    f32x4 acc[3][2][2] = {};
    const int koff = q * 8;
    for (int k0 = 0; k0 < DD; k0 += 32) {
        const int k = k0 + koff;
        const bf16x8 a0 = *(const bf16x8*)(xb + xrow0 + k);
        const bf16x8 a1 = *(const bf16x8*)(xb + xrow1 + k);
#pragma unroll
        for (int nt = 0; nt < 3; nt++) {
            const size_t wrow0 = (size_t)(n_base + nt * 64 + r) * DD;
            const size_t wrow1 = (size_t)(n_base + nt * 64 + 16 + r) * DD;
            bf16x8 b0 = *(const bf16x8*)(wb + wrow0 + k);
            bf16x8 b1 = *(const bf16x8*)(wb + wrow1 + k);
            acc[nt][0][0] = __builtin_amdgcn_mfma_f32_16x16x32_bf16(a0, b0, acc[nt][0][0], 0, 0, 0);
            acc[nt][0][1] = __builtin_amdgcn_mfma_f32_16x16x32_bf16(a0, b1, acc[nt][0][1], 0, 0, 0);
            acc[nt][1][0] = __builtin_amdgcn_mfma_f32_16x16x32_bf16(a1, b0, acc[nt][1][0], 0, 0, 0);
            acc[nt][1][1] = __builtin_amdgcn_mfma_f32_16x16x32_bf16(a1, b1, acc[nt][1][1], 0, 0, 0);
        }
    }

#pragma unroll
    for (int nt = 0; nt < 3; nt++)
#pragma unroll
        for (int mi = 0; mi < 2; mi++)
#pragma unroll
            for (int ni = 0; ni < 2; ni++) {
                const int n = n_base + nt * 64 + ni * 16 + r;
                const float bias = bf[n];
#pragma unroll
                for (int rr = 0; rr < 4; rr++) {
                    const int m = m_blk + mi * 16 + q * 4 + rr;
                    projc[(size_t)m * SIXH + n] = f2bf(acc[nt][mi][ni][rr] + bias);
                }
            }
}

// ---------------------------------------------------------------------------
// Persistent recurrence kernel v11. Grid: NWG=32 x 256 threads (4 waves).
// Wave w owns batches [w*16, w*16+16); block owns j in [wg*16, wg*16+16).
//
// Post-mortem r17: v10's fused detect+load was -50% vs v9 because each poll
// RETRY re-issued 32x16B loads (+vmcnt(0)) -> ~1.3us retry granularity vs
// v9's ~0.2us 4B flag spin. Lesson: detection must be fine-grained; pay the
// bulk load ONCE.
//
// v11 hybrid: producer publishes tagged 16B record [tag|h|tag] FIRE-AND-
// FORGET (keeps v10's good half: no vmcnt drain, no separate flag store).
// Consumer: (a) cheap spin - lane l loads only the 4B tag of producer
// (l&31)'s first-quad record for its own batch (v9-granularity); (b) on
// __all(tag==t), bulk-load the 32 records once, with dual-tag verify-retry
// (expected 1 iter). Correctness rests ONLY on the verify loop; the cheap
// poll is a hint. Watchdogs on both loops (r15 lesson: fail diagnosably).
// ---------------------------------------------------------------------------
__global__ __launch_bounds__(256, 1) void rec_kernel(
    const unsigned short* __restrict__ projc,
    const void* __restrict__ wsv, const void* __restrict__ bsv,
    const int* __restrict__ len32,
    unsigned int* __restrict__ hbuf2, float* __restrict__ cbuf,
    void* __restrict__ outv,
    const int* __restrict__ flags, int t0, int Tc)
{
    const int fp32 = flags[0], i64 = flags[1];
    const int tid  = threadIdx.x;
    const int wv   = tid >> 6;    // wave = batch group (0..3)
    const int lane = tid & 63;
    const int q    = lane >> 4;
    const int r    = lane & 15;
    const int j0   = blockIdx.x * 16;
    const int b    = wv * 16 + r;              // this lane's batch

    // frag-linear W_state slice: [5 gates][16 ki][64 lanes][8 ushort] = 80 KB
    __shared__ unsigned short wlds[5 * 16 * 64 * 8];

    for (int v = tid; v < 5 * 16 * 64; v += 256) {
        const int g  = v >> 10;
        const int ki = (v >> 6) & 15;
        const int ln = v & 63;
        const size_t gaddr = (size_t)(g * HH + j0 + (ln & 15)) * HH + ki * 32 + (ln >> 4) * 8;
        bf16x8 w8;
        if (fp32) w8 = cvt8v((const float*)wsv + gaddr);
        else      w8 = *(const bf16x8*)((const unsigned short*)wsv + gaddr);
        *(bf16x8*)&wlds[(size_t)v * 8] = w8;
    }

    // per-lane persistent state: lane owns batch b x (j = j0+q*4+jj)
    float bs[5][4];
#pragma unroll
    for (int g = 0; g < 5; g++)
#pragma unroll
        for (int jj = 0; jj < 4; jj++)
            bs[g][jj] = fp32 ? ((const float*)bsv)[g * HH + j0 + q * 4 + jj]
                             : bf2f(((const unsigned short*)bsv)[g * HH + j0 + q * 4 + jj]);

    const int len = i64 ? len32[2 * b] : len32[b];

    // PER-GROUP Lmax: max over this wave's 16 batches (uniform within wave)
    int lmax_g = 0;
    for (int i = wv * 16; i < wv * 16 + 16; i++) {
        const int li = i64 ? len32[2 * i] : len32[i];
        lmax_g = (li > lmax_g) ? li : lmax_g;
    }

    float creg[4];
#pragma unroll
    for (int jj = 0; jj < 4; jj++)
        creg[jj] = cbuf[b * HH + j0 + q * 4 + jj];

    // initial projc gate inputs for tl = 0 (overlaps the wlds staging above)
    u16x4 pv[6];
    {
        const unsigned short* pb = projc + (size_t)b * Tc * SIXH + j0 + q * 4;
#pragma unroll
        for (int g = 0; g < 6; g++) pv[g] = *(const u16x4*)(pb + g * HH);
    }

    __syncthreads();   // wlds ready (only barrier in the kernel)

    union HU { i32x4 i; bf16x8 b; };
    union P8 { unsigned short s[4]; unsigned long long u; };

    for (int t = t0; t < t0 + Tc; t++) {
        // ---- dead tail: this GROUP is done past lmax_g; no sync, no GEMM ----
        if (t >= lmax_g) {
            if (fp32) {
                float* op = (float*)outv + ((size_t)b * TT + t) * HH + j0 + q * 4;
                *(float4*)op = make_float4(0.f, 0.f, 0.f, 0.f);
            } else {
                unsigned short* op = (unsigned short*)outv + ((size_t)b * TT + t) * HH + j0 + q * 4;
                *(unsigned long long*)op = 0ull;
            }
            continue;
        }

        // ---- gather h(t): cheap tag detect, then ONE bulk load + verify ----
        const unsigned int* hrow =
            hbuf2 + ((size_t)((t & 1) * BB + b) * 128 + q * 2) * 4;
        i32x4 hq[32];
#define ISSUE_H_LOADS()                                                     \
        _Pragma("unroll")                                                   \
        for (int ki = 0; ki < 16; ki++) {                                   \
            CLOAD16O(hq[2 * ki],     hrow, ki * 128);                       \
            CLOAD16O(hq[2 * ki + 1], hrow, ki * 128 + 16);                  \
        }
        if (t > t0) {
            // (a) fine-grained spin: lane l watches the 4B tag of producer
            //     (l&31)'s first-quad record for this lane's batch b.
            const unsigned int* tagp =
                hbuf2 + ((size_t)((t & 1) * BB + b) * 128 + (lane & 31) * 4) * 4;
            int spin = 0;
            for (;;) {
                unsigned tg;
                CLOAD4(tg, tagp);
                asm volatile("s_waitcnt vmcnt(0)" ::: "memory");
                if (__all(tg == (unsigned)t)) break;
                if (++spin > 131072) break;   // watchdog ~26ms
            }
            // (b) bulk load once + dual-tag verify (sound standalone)
            spin = 0;
            for (;;) {
                ISSUE_H_LOADS();
                asm volatile("s_waitcnt vmcnt(0)" ::: "memory");
                __builtin_amdgcn_sched_barrier(0);
                unsigned bad = 0;
#pragma unroll
                for (int i = 0; i < 32; i++)
                    bad |= (unsigned)((hq[i][0] ^ t) | (hq[i][3] ^ t));
                if (__all(bad == 0)) break;
                if (++spin > 65536) break;    // watchdog: wrong result, not GPU death
            }
        } else {
            // chunk start: producers finished in the previous kernel launch
            ISSUE_H_LOADS();
            asm volatile("s_waitcnt vmcnt(0)" ::: "memory");
            __builtin_amdgcn_sched_barrier(0);
        }
#undef ISSUE_H_LOADS

        // --- GEMM: data already in registers; extract 8 bf16 per ki ---
        f32x4 acc[5] = {};
#pragma unroll
        for (int ki = 0; ki < 16; ki++) {
            HU u;
            u.i = (i32x4){ hq[2 * ki][1], hq[2 * ki][2],
                           hq[2 * ki + 1][1], hq[2 * ki + 1][2] };
#pragma unroll
            for (int g = 0; g < 5; g++) {
                bf16x8 aw = *(const bf16x8*)&wlds[((g * 16 + ki) * 64 + lane) * 8];
                acc[g] = __builtin_amdgcn_mfma_f32_16x16x32_bf16(aw, u.b, acc[g], 0, 0, 0);
            }
        }

        // --- epilogue: lane owns batch b x 4 consecutive j ---
        P8 hp;
        float ov4[4];
#pragma unroll
        for (int jj = 0; jj < 4; jj++) {
            const float i_g = sigm(bf2f(pv[0][jj]) + acc[0][jj] + bs[0][jj]);
            const float f_g = sigm(bf2f(pv[1][jj]) + acc[1][jj] + bs[1][jj]);
            const float g_t = tanh_fast(bf2f(pv[2][jj]) + acc[2][jj] + bs[2][jj]);
            const float o_g = sigm(bf2f(pv[3][jj]) + acc[3][jj] + bs[3][jj]);
            const float hw  = sigm(bf2f(pv[4][jj]) + acc[4][jj] + bs[4][jj]);

            float c_new = i_g * g_t + f_g * creg[jj];
            float ov = o_g * tanh_fast(c_new);
            ov = hw * ov + (1.0f - hw) * bf2f(pv[5][jj]);
            if (t >= len) { ov = 0.0f; c_new = 0.0f; }
            creg[jj] = c_new;
            ov4[jj] = ov;
            hp.s[jj] = f2bf(ov);
        }

        // --- publish h(t+1): ONE tagged 16B store, fire-and-forget ---
        {
            i32x4 st;
            st[0] = t + 1;
            st[1] = (int)(unsigned int)(hp.u & 0xffffffffull);
            st[2] = (int)(unsigned int)(hp.u >> 32);
            st[3] = t + 1;
            unsigned int* hw_ = hbuf2 +
                ((size_t)(((t + 1) & 1) * BB + b) * 128 + (j0 >> 2) + q) * 4;
            CSTORE16(hw_, st);
        }

        // --- off-critical-path: output store + projc prefetch for t+1 ---
        if (fp32) {
            float* op = (float*)outv + ((size_t)b * TT + t) * HH + j0 + q * 4;
            *(float4*)op = make_float4(ov4[0], ov4[1], ov4[2], ov4[3]);
        } else {
            unsigned short* op = (unsigned short*)outv + ((size_t)b * TT + t) * HH + j0 + q * 4;
            *(unsigned long long*)op = hp.u;
        }
        const int tln = t - t0 + 1;
        if (tln < Tc) {
            const unsigned short* pb = projc + ((size_t)b * Tc + tln) * SIXH + j0 + q * 4;
#pragma unroll
            for (int g = 0; g < 6; g++) pv[g] = *(const u16x4*)(pb + g * HH);
        }
    }

    // persist c for chunked mode
#pragma unroll
    for (int jj = 0; jj < 4; jj++)
        cbuf[b * HH + j0 + q * 4 + jj] = creg[jj];
}

// ---------------------------------------------------------------------------
extern "C" void kernel_launch(void* const* d_in, const int* in_sizes, int n_in,
                              void* d_out, int out_size, void* d_ws, size_t ws_size,
                              hipStream_t stream) {
    const void* xv      = d_in[0];
    const int*  len     = (const int*)d_in[1];
    const void* w_in    = d_in[2];
    const void* b_in    = d_in[3];
    const void* w_state = d_in[4];
    const void* b_state = d_in[5];

    char* ws = (char*)d_ws;
    int* flags  = (int*)(ws + WS_FLAGS);
    unsigned int* hbuf2 = (unsigned int*)(ws + WS_H2);
    float* cbuf = (float*)(ws + WS_C);
    unsigned short* xb = (unsigned short*)(ws + WS_XB);
    unsigned short* wb = (unsigned short*)(ws + WS_WB);
    float* bf = (float*)(ws + WS_BF);
    unsigned short* projc = (unsigned short*)(ws + WS_PROJ);

    // Largest proj chunk (timesteps, power of 2, >= 64) fitting ws.
    int tc_shift = 9;
    while (tc_shift > 6 &&
           WS_PROJ + ((size_t)BB << tc_shift) * SIXH * 2 > ws_size) tc_shift--;
    const int Tc = 1 << tc_shift;

    detect_kernel<<<1, 64, 0, stream>>>((const unsigned short*)xv, len, flags);
    // zero tagged h (tags=0 == first step) + c
    hipMemsetAsync(ws + WS_H2, 0, WS_XB - WS_H2, stream);
    convert_kernel<<<2048, 256, 0, stream>>>(xv, w_in, b_in, xb, wb, bf, flags);

    for (int c = 0; c < TT / Tc; c++) {
        const int t0 = c * Tc;
        proj_kernel<<<dim3(SIXH / 192, (BB << tc_shift) >> 6), 256, 0, stream>>>(
            xb, wb, bf, projc, flags, len, t0, tc_shift);
        rec_kernel<<<NWG, 256, 0, stream>>>(projc, w_state, b_state, len,
                                            hbuf2, cbuf, d_out, flags, t0, Tc);
    }
}